// Round 3
// baseline (505.347 us; speedup 1.0000x reference)
//
#include <hip/hip_runtime.h>

#define N_NEURON 500000
#define N_EDGE   10000000

// DT=0.1, TAO_D=2.0, TAO_R=10.0
#define DT_C      0.1f
#define LAMDA_D_C 0.05f
#define LAMDA_R_C 0.01f
#define INV_TAO_D 0.5f

#define NXCD     8
#define NPAD     524288                      // floats per partial copy (2 MiB, line-aligned)
#define WS_RNEW_OFF    0u
#define WS_PARTIAL_OFF (2u * 1024u * 1024u)  // r_new region padded to 2 MiB
#define WS_NEEDED      ((size_t)WS_PARTIAL_OFF + (size_t)NXCD * NPAD * 4u)

// XCD id of the executing block (HW-verified on gfx950: returns 0..7)
__device__ __forceinline__ unsigned get_xcd() {
    unsigned x;
    asm volatile("s_getreg_b32 %0, hwreg(HW_REG_XCC_ID)" : "=s"(x));
    return x & (NXCD - 1);
}

// Kernel 1: per-neuron pointwise update. r_new -> ws, Ieff -> out.
__global__ void neuron_update(const float* __restrict__ Iback,
                              const float* __restrict__ spike,
                              const float* __restrict__ s,
                              const float* __restrict__ r,
                              const float* __restrict__ noise,
                              const float* __restrict__ dt_over_tau,
                              const float* __restrict__ sqrt_coeff,
                              const float* __restrict__ sig,
                              const float* __restrict__ mu,
                              float* __restrict__ r_new,
                              float* __restrict__ out,
                              int n) {
    const float dtau = dt_over_tau[0];
    const float sq   = sqrt_coeff[0];
    const float sg   = sig[0];
    const float m    = mu[0];
    for (int i = blockIdx.x * blockDim.x + threadIdx.x; i < n;
         i += gridDim.x * blockDim.x) {
        float ib  = Iback[i];
        float ibn = ib + dtau * (noise[i] - ib);
        float ieff = ibn / sq * sg + m;
        float sv  = s[i];
        float sn  = sv + LAMDA_R_C * (-sv + spike[i] * INV_TAO_D);
        float rv  = r[i];
        float rn  = rv - LAMDA_D_C * rv + DT_C * sn;
        r_new[i] = rn;
        out[i]   = ieff;
    }
}

// Kernel 2: edge scatter with XCD-local (workgroup-scope) atomics.
// Each block accumulates into its own XCD's 2 MiB partial copy; that copy is
// L2-resident and only ever touched by this XCD, so workgroup-scope atomics
// (which execute in the local L2, the intra-XCD coherence point) are safe.
// Kernel-boundary L2 writeback publishes the results to the reduce kernel.
__global__ __launch_bounds__(256) void edge_scatter_xcd(
        const float* __restrict__ weight,
        const int*   __restrict__ post_arr,
        const int*   __restrict__ pre_arr,
        const float* __restrict__ r_new,
        float*       __restrict__ partial,
        int n_edge) {
    float* mine = partial + (size_t)get_xcd() * NPAD;
    const int tid    = blockIdx.x * blockDim.x + threadIdx.x;
    const int stride = gridDim.x * blockDim.x * 4;
    for (int e = tid * 4; e + 3 < n_edge; e += stride) {
        const int4   p4 = *reinterpret_cast<const int4*>(post_arr + e);
        const int4   q4 = *reinterpret_cast<const int4*>(pre_arr + e);
        const float4 w4 = *reinterpret_cast<const float4*>(weight + e);
        __hip_atomic_fetch_add(&mine[p4.x], w4.x * r_new[q4.x],
                               __ATOMIC_RELAXED, __HIP_MEMORY_SCOPE_WORKGROUP);
        __hip_atomic_fetch_add(&mine[p4.y], w4.y * r_new[q4.y],
                               __ATOMIC_RELAXED, __HIP_MEMORY_SCOPE_WORKGROUP);
        __hip_atomic_fetch_add(&mine[p4.z], w4.z * r_new[q4.z],
                               __ATOMIC_RELAXED, __HIP_MEMORY_SCOPE_WORKGROUP);
        __hip_atomic_fetch_add(&mine[p4.w], w4.w * r_new[q4.w],
                               __ATOMIC_RELAXED, __HIP_MEMORY_SCOPE_WORKGROUP);
    }
    // tail (n_edge not multiple of 4)
    const int tail0 = n_edge & ~3;
    for (int e = tail0 + tid; e < n_edge; e += gridDim.x * blockDim.x) {
        __hip_atomic_fetch_add(&mine[post_arr[e]], weight[e] * r_new[pre_arr[e]],
                               __ATOMIC_RELAXED, __HIP_MEMORY_SCOPE_WORKGROUP);
    }
}

// Kernel 3: out[i] (= Ieff) += sum of the 8 partial copies.
__global__ __launch_bounds__(256) void reduce_partials(
        const float* __restrict__ partial,
        float* __restrict__ out,
        int n4) {
    const int tid    = blockIdx.x * blockDim.x + threadIdx.x;
    const int stride = gridDim.x * blockDim.x;
    const float4* p4 = reinterpret_cast<const float4*>(partial);
    float4*       o4 = reinterpret_cast<float4*>(out);
    const int cstride = NPAD / 4;
    for (int i = tid; i < n4; i += stride) {
        float4 acc = o4[i];
        #pragma unroll
        for (int x = 0; x < NXCD; ++x) {
            const float4 v = p4[(size_t)x * cstride + i];
            acc.x += v.x; acc.y += v.y; acc.z += v.z; acc.w += v.w;
        }
        o4[i] = acc;
    }
}

// Fallback: naive device-scope atomic scatter (only if ws too small)
__global__ void edge_scatter(const float* __restrict__ weight,
                             const int* __restrict__ post,
                             const int* __restrict__ pre,
                             const float* __restrict__ r_new,
                             float* __restrict__ out,
                             int n_edge) {
    for (int e = blockIdx.x * blockDim.x + threadIdx.x; e < n_edge;
         e += gridDim.x * blockDim.x) {
        atomicAdd(&out[post[e]], weight[e] * r_new[pre[e]]);
    }
}

extern "C" void kernel_launch(void* const* d_in, const int* in_sizes, int n_in,
                              void* d_out, int out_size, void* d_ws, size_t ws_size,
                              hipStream_t stream) {
    const float* weight      = (const float*)d_in[0];
    const int*   edges       = (const int*)d_in[1];   // (2, N_EDGE): post then pre
    const float* Iback       = (const float*)d_in[2];
    const float* spike       = (const float*)d_in[3];
    const float* s           = (const float*)d_in[4];
    const float* r           = (const float*)d_in[5];
    const float* noise       = (const float*)d_in[6];
    const float* dt_over_tau = (const float*)d_in[7];
    const float* sqrt_coeff  = (const float*)d_in[8];
    const float* sig         = (const float*)d_in[9];
    const float* mu          = (const float*)d_in[10];

    float* out = (float*)d_out;
    char*  ws  = (char*)d_ws;

    float* r_new   = (float*)(ws + WS_RNEW_OFF);
    float* partial = (float*)(ws + WS_PARTIAL_OFF);

    const int n_edge = in_sizes[0];   // 10M
    const int n      = out_size;      // 500k

    // 1) pointwise neuron update; fills out with Ieff
    {
        const int block = 256;
        const int grid  = (n + block - 1) / block;
        neuron_update<<<grid, block, 0, stream>>>(
            Iback, spike, s, r, noise, dt_over_tau, sqrt_coeff, sig, mu,
            r_new, out, n);
    }

    if (ws_size >= WS_NEEDED) {
        // 2) zero the per-XCD partial copies (ws is NOT re-poisoned between replays)
        hipMemsetAsync(partial, 0, (size_t)NXCD * NPAD * 4u, stream);

        // 3) XCD-local atomic scatter
        edge_scatter_xcd<<<2048, 256, 0, stream>>>(
            weight, edges, edges + n_edge, r_new, partial, n_edge);

        // 4) reduce 8 copies + Ieff -> out   (n is a multiple of 4)
        reduce_partials<<<512, 256, 0, stream>>>(partial, out, n / 4);
    } else {
        edge_scatter<<<4096, 256, 0, stream>>>(
            weight, edges, edges + n_edge, r_new, out, n_edge);
    }
}

// Round 4
// 177.659 us; speedup vs baseline: 2.8445x; 2.8445x over previous
//
#include <hip/hip_runtime.h>

#define N_NEURON 500000
#define N_EDGE   10000000

// DT=0.1, TAO_D=2.0, TAO_R=10.0
#define DT_C      0.1f
#define LAMDA_D_C 0.05f
#define LAMDA_R_C 0.01f
#define INV_TAO_D 0.5f

// ---- binning geometry ----
#define BUCKET_SHIFT 11
#define BUCKET_W     (1 << BUCKET_SHIFT)                          // 2048
#define NBUCKET      ((N_NEURON + BUCKET_W - 1) >> BUCKET_SHIFT)  // 245
#define CAP          45056   // records per bucket (mean ~41.8k padded, +16 sigma)
#define CUR_STRIDE   16      // cursor padded to 64 B: own line+sector per bucket

#define P1_BLOCK 512
#define P1_EPT   32
#define P1_CHUNK (P1_BLOCK * P1_EPT)          // 16384 edges/block
#define LDS_REC  (P1_CHUNK + 4 * NBUCKET)     // 17364 slots (padding headroom)

// ws layout
#define WS_RNEW_OFF    0u
#define WS_CURSOR_OFF  (2u * 1024u * 1024u)
#define WS_REC_OFF     (WS_CURSOR_OFF + 64u * 1024u)
#define WS_NEEDED      ((size_t)WS_REC_OFF + (size_t)NBUCKET * CAP * 8u)  // ~90.4 MB

// Kernel 1: per-neuron pointwise update. r_new -> ws, Ieff -> out (inits out).
__global__ void neuron_update(const float* __restrict__ Iback,
                              const float* __restrict__ spike,
                              const float* __restrict__ s,
                              const float* __restrict__ r,
                              const float* __restrict__ noise,
                              const float* __restrict__ dt_over_tau,
                              const float* __restrict__ sqrt_coeff,
                              const float* __restrict__ sig,
                              const float* __restrict__ mu,
                              float* __restrict__ r_new,
                              float* __restrict__ out,
                              int n) {
    const float dtau = dt_over_tau[0];
    const float sq   = sqrt_coeff[0];
    const float sg   = sig[0];
    const float m    = mu[0];
    for (int i = blockIdx.x * blockDim.x + threadIdx.x; i < n;
         i += gridDim.x * blockDim.x) {
        float ib  = Iback[i];
        float ibn = ib + dtau * (noise[i] - ib);
        float ieff = ibn / sq * sg + m;
        float sv  = s[i];
        float sn  = sv + LAMDA_R_C * (-sv + spike[i] * INV_TAO_D);
        float rv  = r[i];
        float rn  = rv - LAMDA_D_C * rv + DT_C * sn;
        r_new[i] = rn;
        out[i]   = ieff;
    }
}

// Pass 1: block-local counting sort of 16384 edges into 245 bucket runs in
// LDS, then coalesced flush of 32B-aligned runs to per-bucket global lists.
// Global atomics: one padded-sector cursor add per (block,bucket) (~150k).
__global__ __launch_bounds__(P1_BLOCK) void edge_bin(
        const float* __restrict__ weight,
        const int*   __restrict__ post_arr,
        const int*   __restrict__ pre_arr,
        const float* __restrict__ r_new,
        uint2*       __restrict__ records,
        unsigned*    __restrict__ cursor,
        float*       __restrict__ out,
        int n_edge) {
    __shared__ float    val_lds[LDS_REC];
    __shared__ unsigned short post_lds[LDS_REC];
    __shared__ unsigned cnt[NBUCKET];    // real counts
    __shared__ unsigned cntp[NBUCKET];   // padded to x4
    __shared__ unsigned fill[NBUCKET];   // phase-C fill counters
    __shared__ unsigned lbase[NBUCKET];  // block-local exclusive scan of cntp
    __shared__ unsigned base[NBUCKET];   // global reservation offsets

    const int t      = threadIdx.x;
    const int chunk0 = blockIdx.x * P1_CHUNK;

    for (int i = t; i < NBUCKET; i += P1_BLOCK) { cnt[i] = 0; fill[i] = 0; }
    __syncthreads();

    // Phase A: histogram (int4 loads, LDS atomics)
    #pragma unroll
    for (int k = 0; k < P1_EPT / 4; ++k) {
        const int e = chunk0 + (k * P1_BLOCK + t) * 4;
        if (e < n_edge) {
            const int4 p4 = *reinterpret_cast<const int4*>(post_arr + e);
            atomicAdd(&cnt[((unsigned)p4.x) >> BUCKET_SHIFT], 1u);
            atomicAdd(&cnt[((unsigned)p4.y) >> BUCKET_SHIFT], 1u);
            atomicAdd(&cnt[((unsigned)p4.z) >> BUCKET_SHIFT], 1u);
            atomicAdd(&cnt[((unsigned)p4.w) >> BUCKET_SHIFT], 1u);
        }
    }
    __syncthreads();

    // Scan (wave 0): pad counts to x4, exclusive scan -> lbase
    if (t < 64) {
        unsigned carry = 0;
        #pragma unroll
        for (int c = 0; c < 4; ++c) {
            const int idx = c * 64 + t;
            unsigned v = 0;
            if (idx < NBUCKET) v = (cnt[idx] + 3u) & ~3u;
            const unsigned orig = v;
            #pragma unroll
            for (int d = 1; d < 64; d <<= 1) {
                const unsigned u = __shfl_up(v, d);
                if (t >= d) v += u;
            }
            if (idx < NBUCKET) { cntp[idx] = orig; lbase[idx] = carry + v - orig; }
            carry += __shfl(v, 63);
        }
    }
    __syncthreads();

    // Phase B: global reservation, one atomic per bucket (padded cursors)
    if (t < NBUCKET) base[t] = atomicAdd(&cursor[t * CUR_STRIDE], cntp[t]);
    __syncthreads();

    // Phase C: re-read edges (L2-hot), compute v, place records in LDS
    #pragma unroll
    for (int k = 0; k < P1_EPT / 4; ++k) {
        const int e = chunk0 + (k * P1_BLOCK + t) * 4;
        if (e < n_edge) {
            const int4   p4 = *reinterpret_cast<const int4*>(post_arr + e);
            const int4   q4 = *reinterpret_cast<const int4*>(pre_arr + e);
            const float4 w4 = *reinterpret_cast<const float4*>(weight + e);
            const int   ps[4] = {p4.x, p4.y, p4.z, p4.w};
            const int   qs[4] = {q4.x, q4.y, q4.z, q4.w};
            const float wv[4] = {w4.x, w4.y, w4.z, w4.w};
            #pragma unroll
            for (int j = 0; j < 4; ++j) {
                const unsigned b = ((unsigned)ps[j]) >> BUCKET_SHIFT;
                const unsigned l = atomicAdd(&fill[b], 1u);
                const unsigned slot = lbase[b] + l;
                val_lds[slot]  = wv[j] * r_new[qs[j]];
                post_lds[slot] = (unsigned short)(ps[j] & (BUCKET_W - 1));
            }
        }
    }
    __syncthreads();

    // Phase D: coalesced flush. Wave w handles buckets w, w+8, ...
    const int wv = t >> 6, lane = t & 63;
    for (int b = wv; b < NBUCKET; b += (P1_BLOCK / 64)) {
        const unsigned len   = cntp[b];
        const unsigned nreal = cnt[b];
        const unsigned lb    = lbase[b];
        const unsigned gb    = base[b];
        uint2* dst = records + (size_t)b * CAP + gb;
        for (unsigned i = lane; i < len; i += 64) {
            uint2 rec;
            if (i < nreal)
                rec = make_uint2((unsigned)post_lds[lb + i],
                                 __float_as_uint(val_lds[lb + i]));
            else
                rec = make_uint2(0u, 0u);  // pad: adds 0 to first neuron of bucket
            if (gb + i < CAP)
                dst[i] = rec;
            else if (i < nreal)   // overflow fallback (statistically unreachable)
                atomicAdd(&out[(b << BUCKET_SHIFT) + (int)rec.x],
                          __uint_as_float(rec.y));
        }
    }
}

// Pass 2: one block per bucket; LDS accumulate, then non-atomic += into out.
__global__ __launch_bounds__(1024) void bucket_reduce(
        const uint2*    __restrict__ records,
        const unsigned* __restrict__ cursor,
        float*          __restrict__ out,
        int n) {
    __shared__ float acc[BUCKET_W];
    const int b = blockIdx.x;
    const int t = threadIdx.x;
    for (int i = t; i < BUCKET_W; i += 1024) acc[i] = 0.f;
    __syncthreads();

    unsigned count = cursor[b * CUR_STRIDE];
    if (count > CAP) count = CAP;          // count is a multiple of 4
    const uint4* l4 = reinterpret_cast<const uint4*>(records + (size_t)b * CAP);
    const unsigned npair = count >> 1;
    for (unsigned i = t; i < npair; i += 1024) {
        const uint4 r2 = l4[i];
        atomicAdd(&acc[r2.x], __uint_as_float(r2.y));
        atomicAdd(&acc[r2.z], __uint_as_float(r2.w));
    }
    __syncthreads();

    const int g0 = b << BUCKET_SHIFT;
    for (int i = t; i < BUCKET_W; i += 1024) {
        const int g = g0 + i;
        if (g < n) out[g] += acc[i];
    }
}

// Fallback (only if ws too small): naive device-scope atomic scatter
__global__ void edge_scatter(const float* __restrict__ weight,
                             const int* __restrict__ post,
                             const int* __restrict__ pre,
                             const float* __restrict__ r_new,
                             float* __restrict__ out,
                             int n_edge) {
    for (int e = blockIdx.x * blockDim.x + threadIdx.x; e < n_edge;
         e += gridDim.x * blockDim.x) {
        atomicAdd(&out[post[e]], weight[e] * r_new[pre[e]]);
    }
}

extern "C" void kernel_launch(void* const* d_in, const int* in_sizes, int n_in,
                              void* d_out, int out_size, void* d_ws, size_t ws_size,
                              hipStream_t stream) {
    const float* weight      = (const float*)d_in[0];
    const int*   edges       = (const int*)d_in[1];   // (2, N_EDGE): post then pre
    const float* Iback       = (const float*)d_in[2];
    const float* spike       = (const float*)d_in[3];
    const float* s           = (const float*)d_in[4];
    const float* r           = (const float*)d_in[5];
    const float* noise       = (const float*)d_in[6];
    const float* dt_over_tau = (const float*)d_in[7];
    const float* sqrt_coeff  = (const float*)d_in[8];
    const float* sig         = (const float*)d_in[9];
    const float* mu          = (const float*)d_in[10];

    float* out = (float*)d_out;
    char*  ws  = (char*)d_ws;

    float*    r_new   = (float*)(ws + WS_RNEW_OFF);
    unsigned* cursor  = (unsigned*)(ws + WS_CURSOR_OFF);
    uint2*    records = (uint2*)(ws + WS_REC_OFF);

    const int n_edge = in_sizes[0];   // 10M
    const int n      = out_size;      // 500k

    // 1) pointwise neuron update; fills out with Ieff
    {
        const int block = 256;
        const int grid  = (n + block - 1) / block;
        neuron_update<<<grid, block, 0, stream>>>(
            Iback, spike, s, r, noise, dt_over_tau, sqrt_coeff, sig, mu,
            r_new, out, n);
    }

    if (ws_size >= WS_NEEDED) {
        // 2) zero padded cursors every call (ws not re-poisoned between replays)
        hipMemsetAsync(cursor, 0, NBUCKET * CUR_STRIDE * sizeof(unsigned), stream);

        // 3) block-local counting sort -> coalesced bucket lists
        {
            const int grid = (n_edge + P1_CHUNK - 1) / P1_CHUNK;  // 611
            edge_bin<<<grid, P1_BLOCK, 0, stream>>>(
                weight, edges, edges + n_edge, r_new, records, cursor, out, n_edge);
        }

        // 4) per-bucket LDS reduction -> out
        bucket_reduce<<<NBUCKET, 1024, 0, stream>>>(records, cursor, out, n);
    } else {
        edge_scatter<<<4096, 256, 0, stream>>>(
            weight, edges, edges + n_edge, r_new, out, n_edge);
    }
}

// Round 5
// 154.556 us; speedup vs baseline: 3.2697x; 1.1495x over previous
//
#include <hip/hip_runtime.h>
#include <hip/hip_fp16.h>

#define N_NEURON 500000
#define N_EDGE   10000000

// DT=0.1, TAO_D=2.0, TAO_R=10.0
#define DT_C      0.1f
#define LAMDA_D_C 0.05f
#define LAMDA_R_C 0.01f
#define INV_TAO_D 0.5f

// ---- binning geometry ----
#define BUCKET_SHIFT 11
#define BUCKET_W     (1 << BUCKET_SHIFT)                          // 2048
#define NBUCKET      ((N_NEURON + BUCKET_W - 1) >> BUCKET_SHIFT)  // 245
#define CAP          45056   // records/bucket (mean ~41.4k incl pads, +~7 sigma)
#define CUR_STRIDE   16      // cursor on its own 64 B line

#define P1_BLOCK 512
#define P1_EPT   16
#define P1_CHUNK (P1_BLOCK * P1_EPT)          // 8192 edges/block
#define LDS_REC  (P1_CHUNK + 4 * NBUCKET)     // 9172 packed-record slots

// ws layout
#define WS_RNEW_OFF    0u
#define WS_CURSOR_OFF  (2u * 1024u * 1024u)
#define WS_REC_OFF     (WS_CURSOR_OFF + 64u * 1024u)
#define WS_NEEDED      ((size_t)WS_REC_OFF + (size_t)NBUCKET * CAP * 4u)  // ~46 MB

// record = (fp16(value) << 16) | (post & 2047)
__device__ __forceinline__ unsigned pack_rec(int post, float v) {
    const unsigned short hv = __half_as_ushort(__float2half_rn(v));
    return ((unsigned)hv << 16) | ((unsigned)post & (BUCKET_W - 1));
}
__device__ __forceinline__ float rec_val(unsigned rec) {
    return __half2float(__ushort_as_half((unsigned short)(rec >> 16)));
}

// Kernel 1: per-neuron pointwise update (float4). r_new -> ws, Ieff -> out.
__global__ void neuron_update(const float4* __restrict__ Iback,
                              const float4* __restrict__ spike,
                              const float4* __restrict__ s,
                              const float4* __restrict__ r,
                              const float4* __restrict__ noise,
                              const float* __restrict__ dt_over_tau,
                              const float* __restrict__ sqrt_coeff,
                              const float* __restrict__ sig,
                              const float* __restrict__ mu,
                              float4* __restrict__ r_new,
                              float4* __restrict__ out,
                              int n4) {
    const float dtau = dt_over_tau[0];
    const float sq   = sqrt_coeff[0];
    const float sg   = sig[0];
    const float m    = mu[0];
    const int i = blockIdx.x * blockDim.x + threadIdx.x;
    if (i >= n4) return;
    const float4 ib = Iback[i], no = noise[i], sv = s[i], sp = spike[i], rv = r[i];
    float4 ieff, rn;
    {
        float a;
        a = ib.x + dtau * (no.x - ib.x); ieff.x = a / sq * sg + m;
        a = ib.y + dtau * (no.y - ib.y); ieff.y = a / sq * sg + m;
        a = ib.z + dtau * (no.z - ib.z); ieff.z = a / sq * sg + m;
        a = ib.w + dtau * (no.w - ib.w); ieff.w = a / sq * sg + m;
        float sn;
        sn = sv.x + LAMDA_R_C * (-sv.x + sp.x * INV_TAO_D); rn.x = rv.x - LAMDA_D_C * rv.x + DT_C * sn;
        sn = sv.y + LAMDA_R_C * (-sv.y + sp.y * INV_TAO_D); rn.y = rv.y - LAMDA_D_C * rv.y + DT_C * sn;
        sn = sv.z + LAMDA_R_C * (-sv.z + sp.z * INV_TAO_D); rn.z = rv.z - LAMDA_D_C * rv.z + DT_C * sn;
        sn = sv.w + LAMDA_R_C * (-sv.w + sp.w * INV_TAO_D); rn.w = rv.w - LAMDA_D_C * rv.w + DT_C * sn;
    }
    r_new[i] = rn;
    out[i]   = ieff;
}

// Pass 1: block-local counting sort of 8192 edges into 245 bucket runs in
// LDS (4 B packed records), then coalesced flush to per-bucket global lists.
__global__ __launch_bounds__(P1_BLOCK, 6) void edge_bin(
        const float* __restrict__ weight,
        const int*   __restrict__ post_arr,
        const int*   __restrict__ pre_arr,
        const float* __restrict__ r_new,
        unsigned*    __restrict__ records,
        unsigned*    __restrict__ cursor,
        float*       __restrict__ out,
        int n_edge) {
    __shared__ unsigned rec_lds[LDS_REC];
    __shared__ unsigned cnt[NBUCKET];    // real counts
    __shared__ unsigned cntp[NBUCKET];   // padded to x4
    __shared__ unsigned fill[NBUCKET];   // phase-C fill counters
    __shared__ unsigned lbase[NBUCKET];  // block-local exclusive scan of cntp
    __shared__ unsigned base[NBUCKET];   // global reservation offsets

    const int t      = threadIdx.x;
    const int chunk0 = blockIdx.x * P1_CHUNK;

    for (int i = t; i < NBUCKET; i += P1_BLOCK) { cnt[i] = 0; fill[i] = 0; }
    __syncthreads();

    // Phase A: histogram (int4 loads, LDS atomics)
    #pragma unroll
    for (int k = 0; k < P1_EPT / 4; ++k) {
        const int e = chunk0 + (k * P1_BLOCK + t) * 4;
        if (e < n_edge) {
            const int4 p4 = *reinterpret_cast<const int4*>(post_arr + e);
            atomicAdd(&cnt[((unsigned)p4.x) >> BUCKET_SHIFT], 1u);
            atomicAdd(&cnt[((unsigned)p4.y) >> BUCKET_SHIFT], 1u);
            atomicAdd(&cnt[((unsigned)p4.z) >> BUCKET_SHIFT], 1u);
            atomicAdd(&cnt[((unsigned)p4.w) >> BUCKET_SHIFT], 1u);
        }
    }
    __syncthreads();

    // Scan (wave 0): pad counts to x4, exclusive scan -> lbase
    if (t < 64) {
        unsigned carry = 0;
        #pragma unroll
        for (int c = 0; c < 4; ++c) {
            const int idx = c * 64 + t;
            unsigned v = 0;
            if (idx < NBUCKET) v = (cnt[idx] + 3u) & ~3u;
            const unsigned orig = v;
            #pragma unroll
            for (int d = 1; d < 64; d <<= 1) {
                const unsigned u = __shfl_up(v, d);
                if (t >= d) v += u;
            }
            if (idx < NBUCKET) { cntp[idx] = orig; lbase[idx] = carry + v - orig; }
            carry += __shfl(v, 63);
        }
    }
    __syncthreads();

    // Phase B: global reservation, one padded-line atomic per bucket
    if (t < NBUCKET) base[t] = atomicAdd(&cursor[t * CUR_STRIDE], cntp[t]);
    __syncthreads();

    // Phase C: re-read edges (L2-hot), compute v, place packed records in LDS
    #pragma unroll
    for (int k = 0; k < P1_EPT / 4; ++k) {
        const int e = chunk0 + (k * P1_BLOCK + t) * 4;
        if (e < n_edge) {
            const int4   p4 = *reinterpret_cast<const int4*>(post_arr + e);
            const int4   q4 = *reinterpret_cast<const int4*>(pre_arr + e);
            const float4 w4 = *reinterpret_cast<const float4*>(weight + e);
            const int   ps[4] = {p4.x, p4.y, p4.z, p4.w};
            const int   qs[4] = {q4.x, q4.y, q4.z, q4.w};
            const float wv[4] = {w4.x, w4.y, w4.z, w4.w};
            #pragma unroll
            for (int j = 0; j < 4; ++j) {
                const unsigned b = ((unsigned)ps[j]) >> BUCKET_SHIFT;
                const unsigned l = atomicAdd(&fill[b], 1u);
                rec_lds[lbase[b] + l] = pack_rec(ps[j], wv[j] * r_new[qs[j]]);
            }
        }
    }
    __syncthreads();

    // Phase D: coalesced flush. Wave w handles buckets w, w+8, ...
    const int wv = t >> 6, lane = t & 63;
    for (int b = wv; b < NBUCKET; b += (P1_BLOCK / 64)) {
        const unsigned len   = cntp[b];
        const unsigned nreal = cnt[b];
        const unsigned lb    = lbase[b];
        const unsigned gb    = base[b];
        unsigned* dst = records + (size_t)b * CAP + gb;
        for (unsigned i = lane; i < len; i += 64) {
            const unsigned rec = (i < nreal) ? rec_lds[lb + i] : 0u;  // pad adds 0
            if (gb + i < CAP)
                dst[i] = rec;
            else if (i < nreal)   // overflow fallback (statistically unreachable)
                atomicAdd(&out[(b << BUCKET_SHIFT) + (int)(rec & (BUCKET_W - 1))],
                          rec_val(rec));
        }
    }
}

// Pass 2: one block per bucket; LDS accumulate, then non-atomic += into out.
__global__ __launch_bounds__(1024) void bucket_reduce(
        const unsigned* __restrict__ records,
        const unsigned* __restrict__ cursor,
        float*          __restrict__ out,
        int n) {
    __shared__ float acc[BUCKET_W];
    const int b = blockIdx.x;
    const int t = threadIdx.x;
    for (int i = t; i < BUCKET_W; i += 1024) acc[i] = 0.f;
    __syncthreads();

    unsigned count = cursor[b * CUR_STRIDE];
    if (count > CAP) count = CAP;          // multiple of 4
    const uint4* l4 = reinterpret_cast<const uint4*>(records + (size_t)b * CAP);
    const unsigned nquad = count >> 2;
    for (unsigned i = t; i < nquad; i += 1024) {
        const uint4 r4 = l4[i];
        atomicAdd(&acc[r4.x & (BUCKET_W - 1)], rec_val(r4.x));
        atomicAdd(&acc[r4.y & (BUCKET_W - 1)], rec_val(r4.y));
        atomicAdd(&acc[r4.z & (BUCKET_W - 1)], rec_val(r4.z));
        atomicAdd(&acc[r4.w & (BUCKET_W - 1)], rec_val(r4.w));
    }
    __syncthreads();

    const int g0 = b << BUCKET_SHIFT;
    for (int i = t; i < BUCKET_W; i += 1024) {
        const int g = g0 + i;
        if (g < n) out[g] += acc[i];
    }
}

// Fallback (only if ws too small): naive device-scope atomic scatter
__global__ void edge_scatter(const float* __restrict__ weight,
                             const int* __restrict__ post,
                             const int* __restrict__ pre,
                             const float* __restrict__ r_new,
                             float* __restrict__ out,
                             int n_edge) {
    for (int e = blockIdx.x * blockDim.x + threadIdx.x; e < n_edge;
         e += gridDim.x * blockDim.x) {
        atomicAdd(&out[post[e]], weight[e] * r_new[pre[e]]);
    }
}

extern "C" void kernel_launch(void* const* d_in, const int* in_sizes, int n_in,
                              void* d_out, int out_size, void* d_ws, size_t ws_size,
                              hipStream_t stream) {
    const float* weight      = (const float*)d_in[0];
    const int*   edges       = (const int*)d_in[1];   // (2, N_EDGE): post then pre
    const float* Iback       = (const float*)d_in[2];
    const float* spike       = (const float*)d_in[3];
    const float* s           = (const float*)d_in[4];
    const float* r           = (const float*)d_in[5];
    const float* noise       = (const float*)d_in[6];
    const float* dt_over_tau = (const float*)d_in[7];
    const float* sqrt_coeff  = (const float*)d_in[8];
    const float* sig         = (const float*)d_in[9];
    const float* mu          = (const float*)d_in[10];

    float* out = (float*)d_out;
    char*  ws  = (char*)d_ws;

    float*    r_new   = (float*)(ws + WS_RNEW_OFF);
    unsigned* cursor  = (unsigned*)(ws + WS_CURSOR_OFF);
    unsigned* records = (unsigned*)(ws + WS_REC_OFF);

    const int n_edge = in_sizes[0];   // 10M
    const int n      = out_size;      // 500k (multiple of 4)

    // 1) pointwise neuron update; fills out with Ieff
    {
        const int n4    = n / 4;
        const int block = 256;
        const int grid  = (n4 + block - 1) / block;
        neuron_update<<<grid, block, 0, stream>>>(
            (const float4*)Iback, (const float4*)spike, (const float4*)s,
            (const float4*)r, (const float4*)noise,
            dt_over_tau, sqrt_coeff, sig, mu,
            (float4*)r_new, (float4*)out, n4);
    }

    if (ws_size >= WS_NEEDED) {
        // 2) zero padded cursors every call (ws not re-poisoned between replays)
        hipMemsetAsync(cursor, 0, NBUCKET * CUR_STRIDE * sizeof(unsigned), stream);

        // 3) block-local counting sort -> coalesced packed bucket lists
        {
            const int grid = (n_edge + P1_CHUNK - 1) / P1_CHUNK;  // 1221
            edge_bin<<<grid, P1_BLOCK, 0, stream>>>(
                weight, edges, edges + n_edge, r_new, records, cursor, out, n_edge);
        }

        // 4) per-bucket LDS reduction -> out
        bucket_reduce<<<NBUCKET, 1024, 0, stream>>>(records, cursor, out, n);
    } else {
        edge_scatter<<<4096, 256, 0, stream>>>(
            weight, edges, edges + n_edge, r_new, out, n_edge);
    }
}

// Round 6
// 123.861 us; speedup vs baseline: 4.0800x; 1.2478x over previous
//
#include <hip/hip_runtime.h>
#include <hip/hip_fp16.h>

#define N_NEURON 500000
#define N_EDGE   10000000

// DT=0.1, TAO_D=2.0, TAO_R=10.0
#define DT_C      0.1f
#define LAMDA_D_C 0.05f
#define LAMDA_R_C 0.01f
#define INV_TAO_D 0.5f

// ---- binning geometry ----
#define BUCKET_SHIFT 11
#define BUCKET_W     (1 << BUCKET_SHIFT)                          // 2048
#define NBUCKET      ((N_NEURON + BUCKET_W - 1) >> BUCKET_SHIFT)  // 245

#define P1_BLOCK 512
#define P1_EPT   16
#define P1_CHUNK (P1_BLOCK * P1_EPT)                    // 8192 edges/block
#define NCHUNK   ((N_EDGE + P1_CHUNK - 1) / P1_CHUNK)   // 1221
#define OFFS_STRIDE 256                                 // offs row stride (u32)

// ws layout: r_new | offs | records  (no cursors, no memset needed)
#define WS_RNEW_OFF  0u
#define WS_OFFS_OFF  (2u * 1024u * 1024u)
#define WS_REC_OFF   (4u * 1024u * 1024u)
#define WS_NEEDED    ((size_t)WS_REC_OFF + (size_t)NCHUNK * P1_CHUNK * 4u)  // ~44 MB

// record = (fp16(value) << 16) | (post & 2047)
__device__ __forceinline__ unsigned pack_rec(int post, float v) {
    const unsigned short hv = __half_as_ushort(__float2half_rn(v));
    return ((unsigned)hv << 16) | ((unsigned)post & (BUCKET_W - 1));
}
__device__ __forceinline__ float rec_val(unsigned rec) {
    return __half2float(__ushort_as_half((unsigned short)(rec >> 16)));
}

// Kernel 1: per-neuron pointwise update (float4). r_new -> ws, Ieff -> out.
__global__ void neuron_update(const float4* __restrict__ Iback,
                              const float4* __restrict__ spike,
                              const float4* __restrict__ s,
                              const float4* __restrict__ r,
                              const float4* __restrict__ noise,
                              const float* __restrict__ dt_over_tau,
                              const float* __restrict__ sqrt_coeff,
                              const float* __restrict__ sig,
                              const float* __restrict__ mu,
                              float4* __restrict__ r_new,
                              float4* __restrict__ out,
                              int n4) {
    const float dtau = dt_over_tau[0];
    const float sq   = sqrt_coeff[0];
    const float sg   = sig[0];
    const float m    = mu[0];
    const int i = blockIdx.x * blockDim.x + threadIdx.x;
    if (i >= n4) return;
    const float4 ib = Iback[i], no = noise[i], sv = s[i], sp = spike[i], rv = r[i];
    float4 ieff, rn;
    {
        float a;
        a = ib.x + dtau * (no.x - ib.x); ieff.x = a / sq * sg + m;
        a = ib.y + dtau * (no.y - ib.y); ieff.y = a / sq * sg + m;
        a = ib.z + dtau * (no.z - ib.z); ieff.z = a / sq * sg + m;
        a = ib.w + dtau * (no.w - ib.w); ieff.w = a / sq * sg + m;
        float sn;
        sn = sv.x + LAMDA_R_C * (-sv.x + sp.x * INV_TAO_D); rn.x = rv.x - LAMDA_D_C * rv.x + DT_C * sn;
        sn = sv.y + LAMDA_R_C * (-sv.y + sp.y * INV_TAO_D); rn.y = rv.y - LAMDA_D_C * rv.y + DT_C * sn;
        sn = sv.z + LAMDA_R_C * (-sv.z + sp.z * INV_TAO_D); rn.z = rv.z - LAMDA_D_C * rv.z + DT_C * sn;
        sn = sv.w + LAMDA_R_C * (-sv.w + sp.w * INV_TAO_D); rn.w = rv.w - LAMDA_D_C * rv.w + DT_C * sn;
    }
    r_new[i] = rn;
    out[i]   = ieff;
}

// Pass 1: block-local counting sort of 8192 edges; flush is ONE contiguous
// coalesced run per block plus a 246-entry offset table. Zero global atomics.
// LDS = 32 KB records + ~2 KB tables -> 4 blocks/CU (32 waves/CU).
__global__ __launch_bounds__(P1_BLOCK, 8) void edge_bin(
        const float* __restrict__ weight,
        const int*   __restrict__ post_arr,
        const int*   __restrict__ pre_arr,
        const float* __restrict__ r_new,
        unsigned*    __restrict__ records,
        unsigned*    __restrict__ offs,
        int n_edge) {
    __shared__ unsigned rec_lds[P1_CHUNK];
    __shared__ unsigned cnt[NBUCKET];        // histogram, then reused as fill
    __shared__ unsigned lbase[NBUCKET + 1];  // exclusive scan; [NBUCKET] = total

    const int t      = threadIdx.x;
    const int chunk0 = blockIdx.x * P1_CHUNK;

    for (int i = t; i < NBUCKET; i += P1_BLOCK) cnt[i] = 0;
    __syncthreads();

    // Phase A: histogram (int4 loads; n_edge % 4 == 0 so e<n_edge => e+3<n_edge)
    #pragma unroll
    for (int k = 0; k < P1_EPT / 4; ++k) {
        const int e = chunk0 + (k * P1_BLOCK + t) * 4;
        if (e < n_edge) {
            const int4 p4 = *reinterpret_cast<const int4*>(post_arr + e);
            atomicAdd(&cnt[((unsigned)p4.x) >> BUCKET_SHIFT], 1u);
            atomicAdd(&cnt[((unsigned)p4.y) >> BUCKET_SHIFT], 1u);
            atomicAdd(&cnt[((unsigned)p4.z) >> BUCKET_SHIFT], 1u);
            atomicAdd(&cnt[((unsigned)p4.w) >> BUCKET_SHIFT], 1u);
        }
    }
    __syncthreads();

    // Wave-0 exclusive scan of cnt -> lbase[0..245]
    if (t < 64) {
        unsigned carry = 0;
        #pragma unroll
        for (int c = 0; c < 4; ++c) {
            const int idx = c * 64 + t;
            unsigned v = (idx < NBUCKET) ? cnt[idx] : 0u;
            const unsigned orig = v;
            #pragma unroll
            for (int d = 1; d < 64; d <<= 1) {
                const unsigned u = __shfl_up(v, d);
                if (t >= d) v += u;
            }
            if (idx <= NBUCKET) lbase[idx] = carry + v - orig;
            carry += __shfl(v, 63);
        }
    }
    __syncthreads();

    // reset cnt for reuse as fill counters
    for (int i = t; i < NBUCKET; i += P1_BLOCK) cnt[i] = 0;
    __syncthreads();

    // Phase C: re-read edges (L2-hot), compute v, ranked scatter into LDS
    #pragma unroll
    for (int k = 0; k < P1_EPT / 4; ++k) {
        const int e = chunk0 + (k * P1_BLOCK + t) * 4;
        if (e < n_edge) {
            const int4   p4 = *reinterpret_cast<const int4*>(post_arr + e);
            const int4   q4 = *reinterpret_cast<const int4*>(pre_arr + e);
            const float4 w4 = *reinterpret_cast<const float4*>(weight + e);
            const int   ps[4] = {p4.x, p4.y, p4.z, p4.w};
            const int   qs[4] = {q4.x, q4.y, q4.z, q4.w};
            const float wv[4] = {w4.x, w4.y, w4.z, w4.w};
            #pragma unroll
            for (int j = 0; j < 4; ++j) {
                const unsigned b = ((unsigned)ps[j]) >> BUCKET_SHIFT;
                const unsigned l = atomicAdd(&cnt[b], 1u);
                rec_lds[lbase[b] + l] = pack_rec(ps[j], wv[j] * r_new[qs[j]]);
            }
        }
    }
    __syncthreads();

    // Phase D: offset table + fully-coalesced contiguous flush
    if (t <= NBUCKET)
        offs[blockIdx.x * OFFS_STRIDE + t] = lbase[t];
    const unsigned total = lbase[NBUCKET];
    unsigned* dst = records + (size_t)blockIdx.x * P1_CHUNK;
    for (unsigned i = t; i < total; i += P1_BLOCK)
        dst[i] = rec_lds[i];
}

// Pass 2: block b = bucket b. 32 lane-groups of 32 each gather one region's
// run [offs[j][b], offs[j][b+1]) and accumulate into LDS; then out += acc.
__global__ __launch_bounds__(1024) void bucket_reduce(
        const unsigned* __restrict__ records,
        const unsigned* __restrict__ offs,
        float*          __restrict__ out,
        int n, int nchunk) {
    __shared__ float acc[BUCKET_W];
    const int b = blockIdx.x;
    const int t = threadIdx.x;
    for (int i = t; i < BUCKET_W; i += 1024) acc[i] = 0.f;
    __syncthreads();

    const int grp = t >> 5, lane = t & 31;   // 32 groups x 32 lanes
    for (int j = grp; j < nchunk; j += 32) {
        const unsigned s0 = offs[j * OFFS_STRIDE + b];
        const unsigned e0 = offs[j * OFFS_STRIDE + b + 1];
        const unsigned* src = records + (size_t)j * P1_CHUNK;
        for (unsigned i = s0 + lane; i < e0; i += 32) {
            const unsigned rec = src[i];
            atomicAdd(&acc[rec & (BUCKET_W - 1)], rec_val(rec));
        }
    }
    __syncthreads();

    const int g0 = b << BUCKET_SHIFT;
    for (int i = t; i < BUCKET_W; i += 1024) {
        const int g = g0 + i;
        if (g < n) out[g] += acc[i];
    }
}

// Fallback (only if ws too small): naive device-scope atomic scatter
__global__ void edge_scatter(const float* __restrict__ weight,
                             const int* __restrict__ post,
                             const int* __restrict__ pre,
                             const float* __restrict__ r_new,
                             float* __restrict__ out,
                             int n_edge) {
    for (int e = blockIdx.x * blockDim.x + threadIdx.x; e < n_edge;
         e += gridDim.x * blockDim.x) {
        atomicAdd(&out[post[e]], weight[e] * r_new[pre[e]]);
    }
}

extern "C" void kernel_launch(void* const* d_in, const int* in_sizes, int n_in,
                              void* d_out, int out_size, void* d_ws, size_t ws_size,
                              hipStream_t stream) {
    const float* weight      = (const float*)d_in[0];
    const int*   edges       = (const int*)d_in[1];   // (2, N_EDGE): post then pre
    const float* Iback       = (const float*)d_in[2];
    const float* spike       = (const float*)d_in[3];
    const float* s           = (const float*)d_in[4];
    const float* r           = (const float*)d_in[5];
    const float* noise       = (const float*)d_in[6];
    const float* dt_over_tau = (const float*)d_in[7];
    const float* sqrt_coeff  = (const float*)d_in[8];
    const float* sig         = (const float*)d_in[9];
    const float* mu          = (const float*)d_in[10];

    float* out = (float*)d_out;
    char*  ws  = (char*)d_ws;

    float*    r_new   = (float*)(ws + WS_RNEW_OFF);
    unsigned* offs    = (unsigned*)(ws + WS_OFFS_OFF);
    unsigned* records = (unsigned*)(ws + WS_REC_OFF);

    const int n_edge = in_sizes[0];   // 10M
    const int n      = out_size;      // 500k (multiple of 4)

    // 1) pointwise neuron update; fills out with Ieff
    {
        const int n4    = n / 4;
        const int block = 256;
        const int grid  = (n4 + block - 1) / block;
        neuron_update<<<grid, block, 0, stream>>>(
            (const float4*)Iback, (const float4*)spike, (const float4*)s,
            (const float4*)r, (const float4*)noise,
            dt_over_tau, sqrt_coeff, sig, mu,
            (float4*)r_new, (float4*)out, n4);
    }

    const int nchunk = (n_edge + P1_CHUNK - 1) / P1_CHUNK;  // 1221

    if (ws_size >= WS_NEEDED) {
        // 2) block-local counting sort -> block-contiguous packed record runs
        edge_bin<<<nchunk, P1_BLOCK, 0, stream>>>(
            weight, edges, edges + n_edge, r_new, records, offs, n_edge);

        // 3) per-bucket gather + LDS reduction -> out
        bucket_reduce<<<NBUCKET, 1024, 0, stream>>>(records, offs, out, n, nchunk);
    } else {
        edge_scatter<<<4096, 256, 0, stream>>>(
            weight, edges, edges + n_edge, r_new, out, n_edge);
    }
}

// Round 7
// 121.698 us; speedup vs baseline: 4.1525x; 1.0178x over previous
//
#include <hip/hip_runtime.h>
#include <hip/hip_fp16.h>

#define N_NEURON 500000
#define N_EDGE   10000000

// DT=0.1, TAO_D=2.0, TAO_R=10.0
#define DT_C      0.1f
#define LAMDA_D_C 0.05f
#define LAMDA_R_C 0.01f
#define INV_TAO_D 0.5f

// ---- binning geometry ----
#define BUCKET_SHIFT 11
#define BUCKET_W     (1 << BUCKET_SHIFT)                          // 2048
#define NBUCKET      ((N_NEURON + BUCKET_W - 1) >> BUCKET_SHIFT)  // 245

#define P1_BLOCK 512
#define P1_EPT   16
#define P1_CHUNK (P1_BLOCK * P1_EPT)                    // 8192 edges/block
#define NCHUNK   ((N_EDGE + P1_CHUNK - 1) / P1_CHUNK)   // 1221
#define OFFS_STRIDE 256                                 // offs row stride (u32)
#define META_NONE 0xFFFFFFFFu

// ws layout: r_new | offs | records  (no cursors, no memset needed)
#define WS_RNEW_OFF  0u
#define WS_OFFS_OFF  (2u * 1024u * 1024u)
#define WS_REC_OFF   (4u * 1024u * 1024u)
#define WS_NEEDED    ((size_t)WS_REC_OFF + (size_t)NCHUNK * P1_CHUNK * 4u)  // ~44 MB

// record = (fp16(value) << 16) | (post & 2047)
__device__ __forceinline__ unsigned pack_rec(int post, float v) {
    const unsigned short hv = __half_as_ushort(__float2half_rn(v));
    return ((unsigned)hv << 16) | ((unsigned)post & (BUCKET_W - 1));
}
__device__ __forceinline__ float rec_val(unsigned rec) {
    return __half2float(__ushort_as_half((unsigned short)(rec >> 16)));
}

// Kernel 1: r_new only (Ieff is fused into bucket_reduce's epilogue).
__global__ void neuron_update_r(const float4* __restrict__ spike,
                                const float4* __restrict__ s,
                                const float4* __restrict__ r,
                                float4* __restrict__ r_new,
                                int n4) {
    const int i = blockIdx.x * blockDim.x + threadIdx.x;
    if (i >= n4) return;
    const float4 sv = s[i], sp = spike[i], rv = r[i];
    float4 rn;
    float sn;
    sn = sv.x + LAMDA_R_C * (-sv.x + sp.x * INV_TAO_D); rn.x = rv.x - LAMDA_D_C * rv.x + DT_C * sn;
    sn = sv.y + LAMDA_R_C * (-sv.y + sp.y * INV_TAO_D); rn.y = rv.y - LAMDA_D_C * rv.y + DT_C * sn;
    sn = sv.z + LAMDA_R_C * (-sv.z + sp.z * INV_TAO_D); rn.z = rv.z - LAMDA_D_C * rv.z + DT_C * sn;
    sn = sv.w + LAMDA_R_C * (-sv.w + sp.w * INV_TAO_D); rn.w = rv.w - LAMDA_D_C * rv.w + DT_C * sn;
    r_new[i] = rn;
}

// Pass 1: single-touch counting sort. Phase A: one edge read + one LDS rank
// atomic per edge; packed record + (bucket,rank) meta held in REGISTERS
// (statically indexed). Phase B: plain ds_write ranked scatter. Phase D:
// one contiguous coalesced flush per block + 246-entry offset table.
__global__ __launch_bounds__(P1_BLOCK, 8) void edge_bin(
        const float* __restrict__ weight,
        const int*   __restrict__ post_arr,
        const int*   __restrict__ pre_arr,
        const float* __restrict__ r_new,
        unsigned*    __restrict__ records,
        unsigned*    __restrict__ offs,
        int n_edge) {
    __shared__ unsigned rec_lds[P1_CHUNK];
    __shared__ unsigned cnt[NBUCKET];
    __shared__ unsigned lbase[NBUCKET + 1];  // exclusive scan; [NBUCKET]=total

    const int t      = threadIdx.x;
    const int chunk0 = blockIdx.x * P1_CHUNK;

    for (int i = t; i < NBUCKET; i += P1_BLOCK) cnt[i] = 0;
    __syncthreads();

    unsigned rec[P1_EPT];   // packed records (registers, static indexing)
    unsigned meta[P1_EPT];  // (bucket << 13) | rank

    // Phase A: single pass — load, gather, pack, rank (one LDS atomic/edge)
    #pragma unroll
    for (int k = 0; k < P1_EPT / 4; ++k) {
        const int e = chunk0 + (k * P1_BLOCK + t) * 4;
        if (e < n_edge) {   // n_edge % 4 == 0, so full int4 is valid
            const int4   p4 = *reinterpret_cast<const int4*>(post_arr + e);
            const int4   q4 = *reinterpret_cast<const int4*>(pre_arr + e);
            const float4 w4 = *reinterpret_cast<const float4*>(weight + e);
            const int   ps[4] = {p4.x, p4.y, p4.z, p4.w};
            const int   qs[4] = {q4.x, q4.y, q4.z, q4.w};
            const float wv[4] = {w4.x, w4.y, w4.z, w4.w};
            #pragma unroll
            for (int j = 0; j < 4; ++j) {
                const unsigned b = ((unsigned)ps[j]) >> BUCKET_SHIFT;
                const unsigned l = atomicAdd(&cnt[b], 1u);
                rec[k * 4 + j]  = pack_rec(ps[j], wv[j] * r_new[qs[j]]);
                meta[k * 4 + j] = (b << 13) | l;
            }
        } else {
            #pragma unroll
            for (int j = 0; j < 4; ++j) meta[k * 4 + j] = META_NONE;
        }
    }
    __syncthreads();

    // Wave-0 exclusive scan of cnt -> lbase[0..245]
    if (t < 64) {
        unsigned carry = 0;
        #pragma unroll
        for (int c = 0; c < 4; ++c) {
            const int idx = c * 64 + t;
            unsigned v = (idx < NBUCKET) ? cnt[idx] : 0u;
            const unsigned orig = v;
            #pragma unroll
            for (int d = 1; d < 64; d <<= 1) {
                const unsigned u = __shfl_up(v, d);
                if (t >= d) v += u;
            }
            if (idx <= NBUCKET) lbase[idx] = carry + v - orig;
            carry += __shfl(v, 63);
        }
    }
    __syncthreads();

    // Phase B: ranked scatter from registers (plain LDS writes, no atomics)
    #pragma unroll
    for (int k = 0; k < P1_EPT; ++k) {
        if (meta[k] != META_NONE)
            rec_lds[lbase[meta[k] >> 13] + (meta[k] & 0x1FFFu)] = rec[k];
    }
    __syncthreads();

    // Phase D: offset table + fully-coalesced contiguous flush
    if (t <= NBUCKET)
        offs[blockIdx.x * OFFS_STRIDE + t] = lbase[t];
    const unsigned total = lbase[NBUCKET];
    unsigned* dst = records + (size_t)blockIdx.x * P1_CHUNK;
    for (unsigned i = t; i < total; i += P1_BLOCK)
        dst[i] = rec_lds[i];
}

// Pass 2: block b = bucket b. 32 lane-groups of 32 gather the per-region runs
// and accumulate into LDS; epilogue computes Ieff inline and writes
// out[g] = acc + Ieff (covers every g < n exactly once).
__global__ __launch_bounds__(1024) void bucket_reduce(
        const unsigned* __restrict__ records,
        const unsigned* __restrict__ offs,
        const float* __restrict__ Iback,
        const float* __restrict__ noise,
        const float* __restrict__ dt_over_tau,
        const float* __restrict__ sqrt_coeff,
        const float* __restrict__ sig,
        const float* __restrict__ mu,
        float*          __restrict__ out,
        int n, int nchunk) {
    __shared__ float acc[BUCKET_W];
    const int b = blockIdx.x;
    const int t = threadIdx.x;
    for (int i = t; i < BUCKET_W; i += 1024) acc[i] = 0.f;
    __syncthreads();

    const int grp = t >> 5, lane = t & 31;   // 32 groups x 32 lanes
    for (int j = grp; j < nchunk; j += 32) {
        const unsigned s0 = offs[j * OFFS_STRIDE + b];
        const unsigned e0 = offs[j * OFFS_STRIDE + b + 1];
        const unsigned* src = records + (size_t)j * P1_CHUNK;
        for (unsigned i = s0 + lane; i < e0; i += 32) {
            const unsigned rec = src[i];
            atomicAdd(&acc[rec & (BUCKET_W - 1)], rec_val(rec));
        }
    }
    __syncthreads();

    const float dtau = dt_over_tau[0];
    const float sq   = sqrt_coeff[0];
    const float sg   = sig[0];
    const float m    = mu[0];
    const int g0 = b << BUCKET_SHIFT;
    for (int i = t; i < BUCKET_W; i += 1024) {
        const int g = g0 + i;
        if (g < n) {
            const float ib   = Iback[g];
            const float ibn  = ib + dtau * (noise[g] - ib);
            out[g] = acc[i] + (ibn / sq * sg + m);
        }
    }
}

// ---- fallback path (ws too small): full neuron update + naive scatter ----
__global__ void neuron_update_full(const float* __restrict__ Iback,
                                   const float* __restrict__ spike,
                                   const float* __restrict__ s,
                                   const float* __restrict__ r,
                                   const float* __restrict__ noise,
                                   const float* __restrict__ dt_over_tau,
                                   const float* __restrict__ sqrt_coeff,
                                   const float* __restrict__ sig,
                                   const float* __restrict__ mu,
                                   float* __restrict__ r_new,
                                   float* __restrict__ out,
                                   int n) {
    const float dtau = dt_over_tau[0], sq = sqrt_coeff[0], sg = sig[0], m = mu[0];
    for (int i = blockIdx.x * blockDim.x + threadIdx.x; i < n;
         i += gridDim.x * blockDim.x) {
        float ib  = Iback[i];
        float ibn = ib + dtau * (noise[i] - ib);
        float sv  = s[i];
        float sn  = sv + LAMDA_R_C * (-sv + spike[i] * INV_TAO_D);
        float rv  = r[i];
        r_new[i] = rv - LAMDA_D_C * rv + DT_C * sn;
        out[i]   = ibn / sq * sg + m;
    }
}

__global__ void edge_scatter(const float* __restrict__ weight,
                             const int* __restrict__ post,
                             const int* __restrict__ pre,
                             const float* __restrict__ r_new,
                             float* __restrict__ out,
                             int n_edge) {
    for (int e = blockIdx.x * blockDim.x + threadIdx.x; e < n_edge;
         e += gridDim.x * blockDim.x) {
        atomicAdd(&out[post[e]], weight[e] * r_new[pre[e]]);
    }
}

extern "C" void kernel_launch(void* const* d_in, const int* in_sizes, int n_in,
                              void* d_out, int out_size, void* d_ws, size_t ws_size,
                              hipStream_t stream) {
    const float* weight      = (const float*)d_in[0];
    const int*   edges       = (const int*)d_in[1];   // (2, N_EDGE): post then pre
    const float* Iback       = (const float*)d_in[2];
    const float* spike       = (const float*)d_in[3];
    const float* s           = (const float*)d_in[4];
    const float* r           = (const float*)d_in[5];
    const float* noise       = (const float*)d_in[6];
    const float* dt_over_tau = (const float*)d_in[7];
    const float* sqrt_coeff  = (const float*)d_in[8];
    const float* sig         = (const float*)d_in[9];
    const float* mu          = (const float*)d_in[10];

    float* out = (float*)d_out;
    char*  ws  = (char*)d_ws;

    float*    r_new   = (float*)(ws + WS_RNEW_OFF);
    unsigned* offs    = (unsigned*)(ws + WS_OFFS_OFF);
    unsigned* records = (unsigned*)(ws + WS_REC_OFF);

    const int n_edge = in_sizes[0];   // 10M
    const int n      = out_size;      // 500k (multiple of 4)

    const int nchunk = (n_edge + P1_CHUNK - 1) / P1_CHUNK;  // 1221

    if (ws_size >= WS_NEEDED) {
        // 1) r_new only (Ieff fused into pass 2)
        {
            const int n4 = n / 4;
            neuron_update_r<<<(n4 + 255) / 256, 256, 0, stream>>>(
                (const float4*)spike, (const float4*)s, (const float4*)r,
                (float4*)r_new, n4);
        }
        // 2) single-touch counting sort -> block-contiguous packed runs
        edge_bin<<<nchunk, P1_BLOCK, 0, stream>>>(
            weight, edges, edges + n_edge, r_new, records, offs, n_edge);

        // 3) per-bucket gather + LDS reduce + fused Ieff -> out
        bucket_reduce<<<NBUCKET, 1024, 0, stream>>>(
            records, offs, Iback, noise, dt_over_tau, sqrt_coeff, sig, mu,
            out, n, nchunk);
    } else {
        neuron_update_full<<<(n + 255) / 256, 256, 0, stream>>>(
            Iback, spike, s, r, noise, dt_over_tau, sqrt_coeff, sig, mu,
            r_new, out, n);
        edge_scatter<<<4096, 256, 0, stream>>>(
            weight, edges, edges + n_edge, r_new, out, n_edge);
    }
}